// Round 10
// baseline (814.892 us; speedup 1.0000x reference)
//
#include <hip/hip_runtime.h>
#include <stdint.h>

// ---------- types ----------
typedef __bf16  bf16x8 __attribute__((ext_vector_type(8)));
typedef short   s16x8  __attribute__((ext_vector_type(8)));
typedef float   f32x4  __attribute__((ext_vector_type(4)));

__device__ inline short f2bf(float f) {
  union { float f; uint32_t u; } v; v.f = f;
  uint32_t r = v.u + 0x7FFFu + ((v.u >> 16) & 1u);   // RNE
  return (short)(r >> 16);
}

// B=4, H=W=D=16 -> N=4096 tokens/batch, C=512, GROUPS=32 (16 ch/group)

// ---------- GroupNorm stats: 256 blocks (full GPU), per-half partial sums ----------
__global__ __launch_bounds__(256) void gn_stats_k(const float* __restrict__ x,
                                                  float2* __restrict__ sums) {
  int bg2 = blockIdx.x;                       // (b,g,half): bg = bg2>>1
  int bg = bg2 >> 1, half = bg2 & 1;
  int b = bg >> 5, g = bg & 31;
  int tid = threadIdx.x;
  const float* base = x + (size_t)b * 4096 * 512 + (size_t)half * 2048 * 512 + g * 16;
  float s = 0.f, q = 0.f;
  for (int i = tid; i < 8192; i += 256) {
    int n = i >> 2, sub = i & 3;
    float4 v = *(const float4*)(base + (size_t)n * 512 + sub * 4);
    s += v.x + v.y + v.z + v.w;
    q += v.x * v.x + v.y * v.y + v.z * v.z + v.w * v.w;
  }
  for (int off = 32; off > 0; off >>= 1) {
    s += __shfl_down(s, off, 64);
    q += __shfl_down(q, off, 64);
  }
  __shared__ float rs[4], rq[4];
  int w = tid >> 6;
  if ((tid & 63) == 0) { rs[w] = s; rq[w] = q; }
  __syncthreads();
  if (tid == 0) {
    float2 o;
    o.x = rs[0] + rs[1] + rs[2] + rs[3];
    o.y = rq[0] + rq[1] + rq[2] + rq[3];
    sums[bg2] = o;
  }
}

// ---------- GN apply -> bf16 h (derives mean/rstd from partial sums) ----------
__global__ __launch_bounds__(256) void gn_apply_k(const float* __restrict__ x,
                                                  const float2* __restrict__ sums,
                                                  const float* __restrict__ sc,
                                                  const float* __restrict__ bi,
                                                  short* __restrict__ h) {
  size_t i4 = ((size_t)blockIdx.x * 256 + threadIdx.x) * 4;
  int c = (int)(i4 & 511);
  int tok = (int)(i4 >> 9);
  int b = tok >> 12;
  int bg = b * 32 + (c >> 4);
  float2 p0 = sums[bg * 2], p1 = sums[bg * 2 + 1];
  float m = (p0.x + p1.x) * (1.f / 65536.f);
  float var = (p0.y + p1.y) * (1.f / 65536.f) - m * m;
  float r = rsqrtf(var + 1e-6f);
  float4 v = *(const float4*)(x + i4);
  float4 s = *(const float4*)(sc + c);
  float4 bb = *(const float4*)(bi + c);
  short4 o;
  o.x = f2bf((v.x - m) * r * s.x + bb.x);
  o.y = f2bf((v.y - m) * r * s.y + bb.y);
  o.z = f2bf((v.z - m) * r * s.z + bb.z);
  o.w = f2bf((v.w - m) * r * s.w + bb.w);
  *(short4*)(h + i4) = o;
}

// ---------- weights -> bf16, transposed ----------
__global__ __launch_bounds__(256) void wconv_k(const float* __restrict__ wq,
                                               const float* __restrict__ wk,
                                               const float* __restrict__ wv,
                                               const float* __restrict__ wp,
                                               short* __restrict__ wt) {
  int i = blockIdx.x * 256 + threadIdx.x;
  int widx = i >> 18, rem = i & 262143;
  int c = rem >> 9, j = rem & 511;
  const float* w = widx == 0 ? wq : widx == 1 ? wk : widx == 2 ? wv : wp;
  wt[(size_t)widx * 262144 + (size_t)j * 512 + c] = f2bf(w[(size_t)c * 512 + j]);
}

// ---------- fused Q/K/V GEMM: one dispatch, grid (128, 12) ----------
__global__ __launch_bounds__(256) void qkv_gemm_k(const short* __restrict__ A,
                                                  const short* __restrict__ wt,
                                                  const float* __restrict__ bq,
                                                  const float* __restrict__ bk,
                                                  const float* __restrict__ bv,
                                                  short* __restrict__ Qb,
                                                  short* __restrict__ Kb,
                                                  short* __restrict__ Vt) {
  __shared__ __attribute__((aligned(16))) short As[128 * 32];
  __shared__ __attribute__((aligned(16))) short Bs[128 * 32];
  int widx = blockIdx.y >> 2;
  int n0 = (blockIdx.y & 3) * 128;
  const short* Bt = wt + (size_t)widx * 262144;
  const float* bias = widx == 0 ? bq : widx == 1 ? bk : bv;
  const float qscale = widx == 0 ? 0.06375872f : 1.0f;   // 512^-0.5 * log2(e)

  int tid = threadIdx.x;
  int w = tid >> 6, lane = tid & 63, quad = lane >> 4, mrow = lane & 15;
  int wm = w >> 1, wn = w & 1;
  int m0 = blockIdx.x * 128;

  const f32x4 fz = {0.f, 0.f, 0.f, 0.f};
  f32x4 acc[4][4];
#pragma unroll
  for (int i = 0; i < 4; i++)
#pragma unroll
    for (int j = 0; j < 4; j++) acc[i][j] = fz;

  int srow = tid >> 2;
  int scol = (tid & 3) * 8;

  for (int k0 = 0; k0 < 512; k0 += 32) {
    __syncthreads();
#pragma unroll
    for (int i = 0; i < 2; i++) {
      const short* ga = A + (size_t)(m0 + i * 64 + srow) * 512 + k0 + scol;
      const short* gb = Bt + (size_t)(n0 + i * 64 + srow) * 512 + k0 + scol;
      char* la = (char*)As + i * 4096 + w * 1024;
      char* lb = (char*)Bs + i * 4096 + w * 1024;
      __builtin_amdgcn_global_load_lds((__attribute__((address_space(1))) void*)ga,
                                       (__attribute__((address_space(3))) void*)la, 16, 0, 0);
      __builtin_amdgcn_global_load_lds((__attribute__((address_space(1))) void*)gb,
                                       (__attribute__((address_space(3))) void*)lb, 16, 0, 0);
    }
    __syncthreads();
    bf16x8 af[4], bfv[4];
#pragma unroll
    for (int mi = 0; mi < 4; mi++)
      af[mi] = *(const bf16x8*)&As[(wm * 64 + mi * 16 + mrow) * 32 + quad * 8];
#pragma unroll
    for (int ni = 0; ni < 4; ni++)
      bfv[ni] = *(const bf16x8*)&Bs[(wn * 64 + ni * 16 + mrow) * 32 + quad * 8];
#pragma unroll
    for (int mi = 0; mi < 4; mi++)
#pragma unroll
      for (int ni = 0; ni < 4; ni++)
        acc[mi][ni] = __builtin_amdgcn_mfma_f32_16x16x32_bf16(af[mi], bfv[ni], acc[mi][ni], 0, 0, 0);
  }

#pragma unroll
  for (int mi = 0; mi < 4; mi++)
#pragma unroll
    for (int ni = 0; ni < 4; ni++) {
      int col = n0 + wn * 64 + ni * 16 + mrow;
      float bv2 = bias[col];
      if (widx < 2) {
        short* outb = widx ? Kb : Qb;
#pragma unroll
        for (int r = 0; r < 4; r++) {
          int row = m0 + wm * 64 + mi * 16 + quad * 4 + r;
          outb[(size_t)row * 512 + col] = f2bf((acc[mi][ni][r] + bv2) * qscale);
        }
      } else {
        int row0 = m0 + wm * 64 + mi * 16 + quad * 4;
        int b = row0 >> 12, t0 = row0 & 4095;
        short4 o;
        o.x = f2bf(acc[mi][ni][0] + bv2);
        o.y = f2bf(acc[mi][ni][1] + bv2);
        o.z = f2bf(acc[mi][ni][2] + bv2);
        o.w = f2bf(acc[mi][ni][3] + bv2);
        *(short4*)&Vt[(size_t)b * (512 * 4096) + (size_t)col * 4096 + t0] = o;
      }
    }
}

// ---------- GEMM (final projection, validated) ----------
__global__ __launch_bounds__(256) void gemm_k(const short* __restrict__ A,
                                              const short* __restrict__ Bt,
                                              const float* __restrict__ bias,
                                              const float* __restrict__ xres,
                                              float* __restrict__ outf) {
  __shared__ __attribute__((aligned(16))) short As[128 * 32];
  __shared__ __attribute__((aligned(16))) short Bs[128 * 32];
  int tid = threadIdx.x;
  int w = tid >> 6, lane = tid & 63, quad = lane >> 4, mrow = lane & 15;
  int wm = w >> 1, wn = w & 1;
  int m0 = blockIdx.x * 128, n0 = blockIdx.y * 128;

  const f32x4 fz = {0.f, 0.f, 0.f, 0.f};
  f32x4 acc[4][4];
#pragma unroll
  for (int i = 0; i < 4; i++)
#pragma unroll
    for (int j = 0; j < 4; j++) acc[i][j] = fz;

  int srow = tid >> 2;
  int scol = (tid & 3) * 8;

  for (int k0 = 0; k0 < 512; k0 += 32) {
    __syncthreads();
#pragma unroll
    for (int i = 0; i < 2; i++) {
      const short* ga = A + (size_t)(m0 + i * 64 + srow) * 512 + k0 + scol;
      const short* gb = Bt + (size_t)(n0 + i * 64 + srow) * 512 + k0 + scol;
      char* la = (char*)As + i * 4096 + w * 1024;
      char* lb = (char*)Bs + i * 4096 + w * 1024;
      __builtin_amdgcn_global_load_lds((__attribute__((address_space(1))) void*)ga,
                                       (__attribute__((address_space(3))) void*)la, 16, 0, 0);
      __builtin_amdgcn_global_load_lds((__attribute__((address_space(1))) void*)gb,
                                       (__attribute__((address_space(3))) void*)lb, 16, 0, 0);
    }
    __syncthreads();
    bf16x8 af[4], bfv[4];
#pragma unroll
    for (int mi = 0; mi < 4; mi++)
      af[mi] = *(const bf16x8*)&As[(wm * 64 + mi * 16 + mrow) * 32 + quad * 8];
#pragma unroll
    for (int ni = 0; ni < 4; ni++)
      bfv[ni] = *(const bf16x8*)&Bs[(wn * 64 + ni * 16 + mrow) * 32 + quad * 8];
#pragma unroll
    for (int mi = 0; mi < 4; mi++)
#pragma unroll
      for (int ni = 0; ni < 4; ni++)
        acc[mi][ni] = __builtin_amdgcn_mfma_f32_16x16x32_bf16(af[mi], bfv[ni], acc[mi][ni], 0, 0, 0);
  }

#pragma unroll
  for (int mi = 0; mi < 4; mi++)
#pragma unroll
    for (int ni = 0; ni < 4; ni++) {
      int col = n0 + wn * 64 + ni * 16 + mrow;
      float bv = bias[col];
#pragma unroll
      for (int r = 0; r < 4; r++) {
        int row = m0 + wm * 64 + mi * 16 + quad * 4 + r;
        size_t idx = (size_t)row * 512 + col;
        outf[idx] = xres[idx] + acc[mi][ni][r] + bv;
      }
    }
}

// ---------- flash attention v16: 16x16x32 full-channel QK -> NO Sx exchange ----------
// v13=411, v14/v15 pipelining both lost -> the Sx exchange is the structural
// tax (existed only because 32x32-geometry qf[32]=128 VGPR didn't fit). At
// 16x16x32, a FULL 512-ch Q fragment is 64 VGPR (K=32/MFMA). So: 8 waves,
// wave = (qt=w&3: 16-query tile, g=w>>2: 256-ch half). Wave computes its
// entire QK locally -> no k-split, no Sx, no lgkm coupling; softmax/pack/PV
// all wave-local (v7-VALIDATED mappings verbatim: A=K row=key=lane&15,
// B=Q col=query, C row=quad*4+r; reduce shfl_xor 16/32; 8-shuffle pack).
// The barrier degenerates to Ks dbuf rotation + free vmcnt(0) (V consumed
// pre-barrier; staging had the whole body). V direct-to-regs (v12), defer-max
// (v8), Q pre-scaled (v13). VGPR ~ qf64+oacc64+vr64+chains16+tmp ~ 240.
__global__ __launch_bounds__(512, 2) void flash_k(const short* __restrict__ Q,
                                                  const short* __restrict__ K,
                                                  const short* __restrict__ Vt,
                                                  short* __restrict__ O) {
  __shared__ __attribute__((aligned(16))) short Ks[2][16384];   // 2 x 32 KB
  int L = blockIdx.x;
  int b = (L & 7) >> 1;                       // batch -> XCD pair (L%8 round-robin)
  int q0 = (((L >> 3) << 1) | (L & 1)) * 64;
  int tid = threadIdx.x;
  int w = tid >> 6, lane = tid & 63, quad = lane >> 4, m = lane & 15;
  int qt = w & 3;                             // 16-query tile
  int g  = w >> 2;                            // PV channel half (256 ch)
  const size_t batch_off = (size_t)b * 4096 * 512;

  // Q fragments (B-operand 16x16x32: col=query=m, k=quad*8+j), 16 steps = 512 ch
  const short* Qrow = Q + batch_off + (size_t)(q0 + qt * 16 + m) * 512;
  bf16x8 qf[16];
#pragma unroll
  for (int s = 0; s < 16; s++)
    qf[s] = *(const bf16x8*)&Qrow[s * 32 + quad * 8];

  const f32x4 fz = {0.f, 0.f, 0.f, 0.f};
  f32x4 oacc[16];                             // 16q x 256ch (half g)
#pragma unroll
  for (int i = 0; i < 16; i++) oacc[i] = fz;
  float mrun = -1e30f, lrun = 0.f;

  // V base: lane loads V[ch = g*256 + ct*16 + m][t0 + quad*8 .. +8]
  const short* Vb0 = Vt + batch_off + (size_t)(g * 256 + m) * 4096 + quad * 8;

  // ---- prologue: stage K tile 0 (64 chunks of 8ch x 32keys; 4 gloads/wave) ----
#pragma unroll
  for (int i = 0; i < 4; i++) {
    int ksb = w * 8 + i * 2;
    const short* gk = K + batch_off + (size_t)(lane & 31) * 512 + (ksb + (lane >> 5)) * 8;
    __builtin_amdgcn_global_load_lds((__attribute__((address_space(1))) void*)gk,
                                     (__attribute__((address_space(3))) void*)&Ks[0][ksb * 256],
                                     16, 0, 0);
  }
  __syncthreads();

#pragma unroll 1
  for (int it = 0; it < 128; ++it) {
    int buf = it & 1;
    int t0 = it * 32;
    // 1. stage K(it+1) -> Ks[buf^1] (read next iter, after this iter's barrier)
    if (it < 127) {
#pragma unroll
      for (int i = 0; i < 4; i++) {
        int ksb = w * 8 + i * 2;
        const short* gk = K + batch_off + (size_t)(t0 + 32 + (lane & 31)) * 512 +
                          (size_t)(ksb + (lane >> 5)) * 8;
        __builtin_amdgcn_global_load_lds((__attribute__((address_space(1))) void*)gk,
                                         (__attribute__((address_space(3))) void*)&Ks[buf ^ 1][ksb * 256],
                                         16, 0, 0);
      }
    }
    // 2. QK^T full 512 ch (v7 layout): A=K (row=key m), B=Q; 4 acc chains
    f32x4 s0a = fz, s0b = fz, s1a = fz, s1b = fz;
#pragma unroll
    for (int s = 0; s < 16; s++) {
      bf16x8 k0 = *(const bf16x8*)&Ks[buf][((s * 4 + quad) * 32 + m) * 8];
      bf16x8 k1 = *(const bf16x8*)&Ks[buf][((s * 4 + quad) * 32 + 16 + m) * 8];
      if (s & 1) {
        s0b = __builtin_amdgcn_mfma_f32_16x16x32_bf16(k0, qf[s], s0b, 0, 0, 0);
        s1b = __builtin_amdgcn_mfma_f32_16x16x32_bf16(k1, qf[s], s1b, 0, 0, 0);
      } else {
        s0a = __builtin_amdgcn_mfma_f32_16x16x32_bf16(k0, qf[s], s0a, 0, 0, 0);
        s1a = __builtin_amdgcn_mfma_f32_16x16x32_bf16(k1, qf[s], s1a, 0, 0, 0);
      }
    }
    // 3. V loads (16 x 16B -> regs; latency hides under softmax+pack)
    bf16x8 vr[16];
#pragma unroll
    for (int ct = 0; ct < 16; ct++)
      vr[ct] = *(const bf16x8*)(Vb0 + (size_t)ct * 65536 + t0);
    // 4. softmax (wave-local; Q pre-scaled): lane = query m, keys quad*4+r (+16)
    float v0[4], v1[4];
    float mx = -1e30f;
#pragma unroll
    for (int r = 0; r < 4; r++) {
      v0[r] = s0a[r] + s0b[r];
      v1[r] = s1a[r] + s1b[r];
      mx = fmaxf(mx, fmaxf(v0[r], v1[r]));
    }
    mx = fmaxf(mx, __shfl_xor(mx, 16, 64));
    mx = fmaxf(mx, __shfl_xor(mx, 32, 64));
    if (__any(mx > mrun + 8.0f)) {            // defer-max (THR=8, validated)
      float mn = fmaxf(mrun, mx);
      float alpha = exp2f(mrun - mn);
      mrun = mn;
      lrun *= alpha;
      float al[4];
#pragma unroll
      for (int r = 0; r < 4; r++) al[r] = __shfl(alpha, quad * 4 + r, 64);
#pragma unroll
      for (int ct = 0; ct < 16; ct++)
#pragma unroll
        for (int r = 0; r < 4; r++) oacc[ct][r] *= al[r];
    }
    float p0[4], p1[4];
    float sum = 0.f;
#pragma unroll
    for (int r = 0; r < 4; r++) {
      p0[r] = exp2f(v0[r] - mrun);
      p1[r] = exp2f(v1[r] - mrun);
      sum += p0[r] + p1[r];
    }
    sum += __shfl_xor(sum, 16, 64);
    sum += __shfl_xor(sum, 32, 64);
    lrun += sum;
    // 5. P -> A-frag (v7-validated 8-shuffle pack; cvt_pk replaces f2bf pair)
    uint32_t pk[4];
#pragma unroll
    for (int r = 0; r < 4; r++)
      asm("v_cvt_pk_bf16_f32 %0, %1, %2" : "=v"(pk[r]) : "v"(p0[r]), "v"(p1[r]));
    s16x8 pfs;
#pragma unroll
    for (int j = 0; j < 8; j++) {
      int src = ((((quad & 1) * 2 + (j >> 2)) << 4) | m);
      uint32_t pv = (uint32_t)__shfl((int)pk[j & 3], src, 64);
      pfs[j] = (short)(quad < 2 ? (pv & 0xffffu) : (pv >> 16));
    }
    bf16x8 pf = __builtin_bit_cast(bf16x8, pfs);
    // 6. O += P @ V (B=V from registers)
#pragma unroll
    for (int ct = 0; ct < 16; ct++)
      oacc[ct] = __builtin_amdgcn_mfma_f32_16x16x32_bf16(pf, vr[ct], oacc[ct], 0, 0, 0);
    // 7. barrier: only guards Ks rotation; staging drained (free — V consumed)
    asm volatile("s_waitcnt vmcnt(0)" ::: "memory");
    __builtin_amdgcn_s_barrier();
    asm volatile("" ::: "memory");
  }
  // ---- epilogue: O /= l, store bf16 (row = q0+qt*16+quad*4+r, col = g*256+ct*16+m) ----
  float invl = 1.f / lrun;
  float ir[4];
#pragma unroll
  for (int r = 0; r < 4; r++) ir[r] = __shfl(invl, quad * 4 + r, 64);
#pragma unroll
  for (int ct = 0; ct < 16; ct++)
#pragma unroll
    for (int r = 0; r < 4; r++) {
      int row = q0 + qt * 16 + quad * 4 + r;
      int col = g * 256 + ct * 16 + m;
      O[batch_off + (size_t)row * 512 + col] = f2bf(oacc[ct][r] * ir[r]);
    }
}

extern "C" void kernel_launch(void* const* d_in, const int* in_sizes, int n_in,
                              void* d_out, int out_size, void* d_ws, size_t ws_size,
                              hipStream_t stream) {
  const float* x  = (const float*)d_in[0];
  const float* gs = (const float*)d_in[1];
  const float* gb = (const float*)d_in[2];
  const float* wq = (const float*)d_in[3];
  const float* bq = (const float*)d_in[4];
  const float* wk = (const float*)d_in[5];
  const float* bk = (const float*)d_in[6];
  const float* wv = (const float*)d_in[7];
  const float* bv = (const float*)d_in[8];
  const float* wp = (const float*)d_in[9];
  const float* bp = (const float*)d_in[10];
  float* out = (float*)d_out;

  // ---- workspace layout (~35.7 MB; Q/K live in d_out until final GEMM) ----
  char* ws = (char*)d_ws;
  float2* sums = (float2*)ws;                             // 256 float2 (2 KB)
  short* h    = (short*)(ws + 4096);                      // 16384*512 bf16 (16.78 MB)
  short* wt   = (short*)(ws + 4096 + 16777216);           // 4*512*512 bf16 (2 MB)
  short* Vt   = (short*)(ws + 4096 + 16777216 + 2097152); // [b][c][t] bf16 (16.78 MB)
  short* Qb   = (short*)d_out;                            // 16.78 MB in d_out
  short* Kb   = Qb + 8388608;                             // 16.78 MB in d_out
  short* Ob   = h;                                        // alias: h dead after V GEMM

  gn_stats_k<<<256, 256, 0, stream>>>(x, sums);
  gn_apply_k<<<8192, 256, 0, stream>>>(x, sums, gs, gb, h);
  wconv_k<<<4096, 256, 0, stream>>>(wq, wk, wv, wp, wt);
  qkv_gemm_k<<<dim3(128, 12), 256, 0, stream>>>(h, wt, bq, bk, bv, Qb, Kb, Vt);
  flash_k<<<256, 512, 0, stream>>>(Qb, Kb, Vt, Ob);
  // final projection reads Ob (=h space), x, wt_p; writes d_out (overwrites Q/K)
  gemm_k<<<dim3(128, 4), 256, 0, stream>>>(Ob, wt + 786432, bp, x, out);
}

// Round 11
// 698.651 us; speedup vs baseline: 1.1664x; 1.1664x over previous
//
#include <hip/hip_runtime.h>
#include <stdint.h>

// ---------- types ----------
typedef __bf16  bf16x8 __attribute__((ext_vector_type(8)));
typedef float   f32x4  __attribute__((ext_vector_type(4)));
typedef float   f32x16 __attribute__((ext_vector_type(16)));
typedef uint32_t u32x4 __attribute__((ext_vector_type(4)));

__device__ inline short f2bf(float f) {
  union { float f; uint32_t u; } v; v.f = f;
  uint32_t r = v.u + 0x7FFFu + ((v.u >> 16) & 1u);   // RNE
  return (short)(r >> 16);
}

// B=4, H=W=D=16 -> N=4096 tokens/batch, C=512, GROUPS=32 (16 ch/group)

// ---------- GroupNorm stats: 256 blocks (full GPU), per-half partial sums ----------
__global__ __launch_bounds__(256) void gn_stats_k(const float* __restrict__ x,
                                                  float2* __restrict__ sums) {
  int bg2 = blockIdx.x;                       // (b,g,half): bg = bg2>>1
  int bg = bg2 >> 1, half = bg2 & 1;
  int b = bg >> 5, g = bg & 31;
  int tid = threadIdx.x;
  const float* base = x + (size_t)b * 4096 * 512 + (size_t)half * 2048 * 512 + g * 16;
  float s = 0.f, q = 0.f;
  for (int i = tid; i < 8192; i += 256) {
    int n = i >> 2, sub = i & 3;
    float4 v = *(const float4*)(base + (size_t)n * 512 + sub * 4);
    s += v.x + v.y + v.z + v.w;
    q += v.x * v.x + v.y * v.y + v.z * v.z + v.w * v.w;
  }
  for (int off = 32; off > 0; off >>= 1) {
    s += __shfl_down(s, off, 64);
    q += __shfl_down(q, off, 64);
  }
  __shared__ float rs[4], rq[4];
  int w = tid >> 6;
  if ((tid & 63) == 0) { rs[w] = s; rq[w] = q; }
  __syncthreads();
  if (tid == 0) {
    float2 o;
    o.x = rs[0] + rs[1] + rs[2] + rs[3];
    o.y = rq[0] + rq[1] + rq[2] + rq[3];
    sums[bg2] = o;
  }
}

// ---------- GN apply -> bf16 h (derives mean/rstd from partial sums) ----------
__global__ __launch_bounds__(256) void gn_apply_k(const float* __restrict__ x,
                                                  const float2* __restrict__ sums,
                                                  const float* __restrict__ sc,
                                                  const float* __restrict__ bi,
                                                  short* __restrict__ h) {
  size_t i4 = ((size_t)blockIdx.x * 256 + threadIdx.x) * 4;
  int c = (int)(i4 & 511);
  int tok = (int)(i4 >> 9);
  int b = tok >> 12;
  int bg = b * 32 + (c >> 4);
  float2 p0 = sums[bg * 2], p1 = sums[bg * 2 + 1];
  float m = (p0.x + p1.x) * (1.f / 65536.f);
  float var = (p0.y + p1.y) * (1.f / 65536.f) - m * m;
  float r = rsqrtf(var + 1e-6f);
  float4 v = *(const float4*)(x + i4);
  float4 s = *(const float4*)(sc + c);
  float4 bb = *(const float4*)(bi + c);
  short4 o;
  o.x = f2bf((v.x - m) * r * s.x + bb.x);
  o.y = f2bf((v.y - m) * r * s.y + bb.y);
  o.z = f2bf((v.z - m) * r * s.z + bb.z);
  o.w = f2bf((v.w - m) * r * s.w + bb.w);
  *(short4*)(h + i4) = o;
}

// ---------- weights -> bf16, transposed ----------
__global__ __launch_bounds__(256) void wconv_k(const float* __restrict__ wq,
                                               const float* __restrict__ wk,
                                               const float* __restrict__ wv,
                                               const float* __restrict__ wp,
                                               short* __restrict__ wt) {
  int i = blockIdx.x * 256 + threadIdx.x;
  int widx = i >> 18, rem = i & 262143;
  int c = rem >> 9, j = rem & 511;
  const float* w = widx == 0 ? wq : widx == 1 ? wk : widx == 2 ? wv : wp;
  wt[(size_t)widx * 262144 + (size_t)j * 512 + c] = f2bf(w[(size_t)c * 512 + j]);
}

// ---------- fused Q/K/V GEMM: one dispatch, grid (128, 12) ----------
__global__ __launch_bounds__(256) void qkv_gemm_k(const short* __restrict__ A,
                                                  const short* __restrict__ wt,
                                                  const float* __restrict__ bq,
                                                  const float* __restrict__ bk,
                                                  const float* __restrict__ bv,
                                                  short* __restrict__ Qb,
                                                  short* __restrict__ Kb,
                                                  short* __restrict__ Vt) {
  __shared__ __attribute__((aligned(16))) short As[128 * 32];
  __shared__ __attribute__((aligned(16))) short Bs[128 * 32];
  int widx = blockIdx.y >> 2;
  int n0 = (blockIdx.y & 3) * 128;
  const short* Bt = wt + (size_t)widx * 262144;
  const float* bias = widx == 0 ? bq : widx == 1 ? bk : bv;
  const float qscale = widx == 0 ? 0.06375872f : 1.0f;   // 512^-0.5 * log2(e)

  int tid = threadIdx.x;
  int w = tid >> 6, lane = tid & 63, quad = lane >> 4, mrow = lane & 15;
  int wm = w >> 1, wn = w & 1;
  int m0 = blockIdx.x * 128;

  const f32x4 fz = {0.f, 0.f, 0.f, 0.f};
  f32x4 acc[4][4];
#pragma unroll
  for (int i = 0; i < 4; i++)
#pragma unroll
    for (int j = 0; j < 4; j++) acc[i][j] = fz;

  int srow = tid >> 2;
  int scol = (tid & 3) * 8;

  for (int k0 = 0; k0 < 512; k0 += 32) {
    __syncthreads();
#pragma unroll
    for (int i = 0; i < 2; i++) {
      const short* ga = A + (size_t)(m0 + i * 64 + srow) * 512 + k0 + scol;
      const short* gb = Bt + (size_t)(n0 + i * 64 + srow) * 512 + k0 + scol;
      char* la = (char*)As + i * 4096 + w * 1024;
      char* lb = (char*)Bs + i * 4096 + w * 1024;
      __builtin_amdgcn_global_load_lds((__attribute__((address_space(1))) void*)ga,
                                       (__attribute__((address_space(3))) void*)la, 16, 0, 0);
      __builtin_amdgcn_global_load_lds((__attribute__((address_space(1))) void*)gb,
                                       (__attribute__((address_space(3))) void*)lb, 16, 0, 0);
    }
    __syncthreads();
    bf16x8 af[4], bfv[4];
#pragma unroll
    for (int mi = 0; mi < 4; mi++)
      af[mi] = *(const bf16x8*)&As[(wm * 64 + mi * 16 + mrow) * 32 + quad * 8];
#pragma unroll
    for (int ni = 0; ni < 4; ni++)
      bfv[ni] = *(const bf16x8*)&Bs[(wn * 64 + ni * 16 + mrow) * 32 + quad * 8];
#pragma unroll
    for (int mi = 0; mi < 4; mi++)
#pragma unroll
      for (int ni = 0; ni < 4; ni++)
        acc[mi][ni] = __builtin_amdgcn_mfma_f32_16x16x32_bf16(af[mi], bfv[ni], acc[mi][ni], 0, 0, 0);
  }

#pragma unroll
  for (int mi = 0; mi < 4; mi++)
#pragma unroll
    for (int ni = 0; ni < 4; ni++) {
      int col = n0 + wn * 64 + ni * 16 + mrow;
      float bv2 = bias[col];
      if (widx < 2) {
        short* outb = widx ? Kb : Qb;
#pragma unroll
        for (int r = 0; r < 4; r++) {
          int row = m0 + wm * 64 + mi * 16 + quad * 4 + r;
          outb[(size_t)row * 512 + col] = f2bf((acc[mi][ni][r] + bv2) * qscale);
        }
      } else {
        int row0 = m0 + wm * 64 + mi * 16 + quad * 4;
        int b = row0 >> 12, t0 = row0 & 4095;
        short4 o;
        o.x = f2bf(acc[mi][ni][0] + bv2);
        o.y = f2bf(acc[mi][ni][1] + bv2);
        o.z = f2bf(acc[mi][ni][2] + bv2);
        o.w = f2bf(acc[mi][ni][3] + bv2);
        *(short4*)&Vt[(size_t)b * (512 * 4096) + (size_t)col * 4096 + t0] = o;
      }
    }
}

// ---------- GEMM (final projection, validated) ----------
__global__ __launch_bounds__(256) void gemm_k(const short* __restrict__ A,
                                              const short* __restrict__ Bt,
                                              const float* __restrict__ bias,
                                              const float* __restrict__ xres,
                                              float* __restrict__ outf) {
  __shared__ __attribute__((aligned(16))) short As[128 * 32];
  __shared__ __attribute__((aligned(16))) short Bs[128 * 32];
  int tid = threadIdx.x;
  int w = tid >> 6, lane = tid & 63, quad = lane >> 4, mrow = lane & 15;
  int wm = w >> 1, wn = w & 1;
  int m0 = blockIdx.x * 128, n0 = blockIdx.y * 128;

  const f32x4 fz = {0.f, 0.f, 0.f, 0.f};
  f32x4 acc[4][4];
#pragma unroll
  for (int i = 0; i < 4; i++)
#pragma unroll
    for (int j = 0; j < 4; j++) acc[i][j] = fz;

  int srow = tid >> 2;
  int scol = (tid & 3) * 8;

  for (int k0 = 0; k0 < 512; k0 += 32) {
    __syncthreads();
#pragma unroll
    for (int i = 0; i < 2; i++) {
      const short* ga = A + (size_t)(m0 + i * 64 + srow) * 512 + k0 + scol;
      const short* gb = Bt + (size_t)(n0 + i * 64 + srow) * 512 + k0 + scol;
      char* la = (char*)As + i * 4096 + w * 1024;
      char* lb = (char*)Bs + i * 4096 + w * 1024;
      __builtin_amdgcn_global_load_lds((__attribute__((address_space(1))) void*)ga,
                                       (__attribute__((address_space(3))) void*)la, 16, 0, 0);
      __builtin_amdgcn_global_load_lds((__attribute__((address_space(1))) void*)gb,
                                       (__attribute__((address_space(3))) void*)lb, 16, 0, 0);
    }
    __syncthreads();
    bf16x8 af[4], bfv[4];
#pragma unroll
    for (int mi = 0; mi < 4; mi++)
      af[mi] = *(const bf16x8*)&As[(wm * 64 + mi * 16 + mrow) * 32 + quad * 8];
#pragma unroll
    for (int ni = 0; ni < 4; ni++)
      bfv[ni] = *(const bf16x8*)&Bs[(wn * 64 + ni * 16 + mrow) * 32 + quad * 8];
#pragma unroll
    for (int mi = 0; mi < 4; mi++)
#pragma unroll
      for (int ni = 0; ni < 4; ni++)
        acc[mi][ni] = __builtin_amdgcn_mfma_f32_16x16x32_bf16(af[mi], bfv[ni], acc[mi][ni], 0, 0, 0);
  }

#pragma unroll
  for (int mi = 0; mi < 4; mi++)
#pragma unroll
    for (int ni = 0; ni < 4; ni++) {
      int col = n0 + wn * 64 + ni * 16 + mrow;
      float bv = bias[col];
#pragma unroll
      for (int r = 0; r < 4; r++) {
        int row = m0 + wm * 64 + mi * 16 + quad * 4 + r;
        size_t idx = (size_t)row * 512 + col;
        outf[idx] = xres[idx] + acc[mi][ni][r] + bv;
      }
    }
}

// ---------- flash attention v17: EXACT v13 champion (411us) + validated riders ----------
// v14 (spill), v15 (longer post-barrier path), v16 (2x K-reads + bpermutes) all
// lost to v13 -> v13's 32x32 k-split + Sx + barrier-in-middle is a real local
// optimum (HW already overlaps PV(it) || QK(it+1) across the counted-vmcnt
// barrier). v17 = v13 byte-identical structure + three isolated riders:
//  1. tree max/sum reductions (depth 4 vs serial 15; validated in v15's pass)
//  2. halved pack shuffle (pre-select Z=hi?A:C, one shfl_xor per word-pair;
//     mapping identical, validated in v15's pass)
//  3. s_setprio(1) around the QK MFMA cluster (T5: attn +4-7%)
__global__ __launch_bounds__(512, 2) void flash_k(const short* __restrict__ Q,
                                                  const short* __restrict__ K,
                                                  const short* __restrict__ Vt,
                                                  short* __restrict__ O) {
  __shared__ __attribute__((aligned(16))) short Ks[2][16384];   // 64 KB
  __shared__ __attribute__((aligned(16))) float Sx[2][8192];    // 64 KB exchange (dbuf)
  int L = blockIdx.x;
  int b = (L & 7) >> 1;                       // batch -> XCD pair (L%8 round-robin)
  int q0 = (((L >> 3) << 1) | (L & 1)) * 64;
  int tid = threadIdx.x;
  int w = tid >> 6, lane = tid & 63;
  int ql = lane & 31, hi = lane >> 5;
  int qh = w & 1;                             // query half (32 queries)
  int gg = w >> 1;                            // PV channel quarter (128 ch)
  int kj = gg & 1;                            // QK k-split half (256 ch)
  const size_t batch_off = (size_t)b * 4096 * 512;

  // Q fragments (B-operand 32x32x16: col=query=ql, k=hi*8+j); Q is pre-scaled
  const short* Qrow = Q + batch_off + (size_t)(q0 + qh * 32 + ql) * 512 + kj * 256;
  bf16x8 qf[16];
#pragma unroll
  for (int s = 0; s < 16; s++)
    qf[s] = *(const bf16x8*)&Qrow[s * 16 + hi * 8];

  const f32x16 fz16 = {0,0,0,0,0,0,0,0,0,0,0,0,0,0,0,0};
  f32x16 oacc[4];                             // 32q x 128ch (quarter gg)
#pragma unroll
  for (int i = 0; i < 4; i++) oacc[i] = fz16;
  float mrun = -1e30f, lrun = 0.f;

  // V direct-load base: lane reads V[ch = gg*128 + cb*32 + ql][t0 + ks*16 + hi*8]
  const short* Vb0 = Vt + batch_off + (size_t)(gg * 128 + ql) * 4096 + hi * 8;

  // ---- prologue: stage K tile 0 into buf 0 (32 slices of 1 KB, 4/wave) ----
#pragma unroll
  for (int i = 0; i < 4; i++) {
    int s = w * 4 + i;                        // K slice = k-step s (1 KB)
    const short* gk = K + batch_off + (size_t)ql * 512 + s * 16 + hi * 8;
    __builtin_amdgcn_global_load_lds((__attribute__((address_space(1))) void*)gk,
                                     (__attribute__((address_space(3))) void*)&Ks[0][s * 512],
                                     16, 0, 0);
  }
  __syncthreads();                            // one-time full drain

#pragma unroll 1
  for (int it = 0; it < 128; ++it) {
    int t0 = it * 32;
    int buf = it & 1;
    // ---- issue next K tile FIRST (drained by vmcnt(8) at this iter's barrier) ----
    if (it < 127) {
      int t1 = t0 + 32;
#pragma unroll
      for (int i = 0; i < 4; i++) {
        int s = w * 4 + i;
        const short* gk = K + batch_off + (size_t)(t1 + ql) * 512 + s * 16 + hi * 8;
        __builtin_amdgcn_global_load_lds((__attribute__((address_space(1))) void*)gk,
                                         (__attribute__((address_space(3))) void*)&Ks[buf ^ 1][s * 512],
                                         16, 0, 0);
      }
    }
    asm volatile("" ::: "memory");            // staging precedes V loads in vmem order
    // ---- V loads for THIS iter: 8 x 16B straight to VGPRs (consumed at PV) ----
    bf16x8 vr[4][2];
#pragma unroll
    for (int cb = 0; cb < 4; cb++)
#pragma unroll
      for (int ks = 0; ks < 2; ks++)
        vr[cb][ks] = *(const bf16x8*)(Vb0 + (size_t)cb * 32 * 4096 + t0 + ks * 16);
    // ---- QK^T partial (this wave's 256 channels): A=K rows=keys, B=Q; 4 chains ----
    __builtin_amdgcn_s_setprio(1);
    f32x16 s0 = fz16, s1 = fz16, s2 = fz16, s3 = fz16;
#pragma unroll
    for (int s = 0; s < 16; s += 4) {
      bf16x8 k0 = *(const bf16x8*)&Ks[buf][(kj * 16 + s + 0) * 512 + lane * 8];
      bf16x8 k1 = *(const bf16x8*)&Ks[buf][(kj * 16 + s + 1) * 512 + lane * 8];
      bf16x8 k2 = *(const bf16x8*)&Ks[buf][(kj * 16 + s + 2) * 512 + lane * 8];
      bf16x8 k3 = *(const bf16x8*)&Ks[buf][(kj * 16 + s + 3) * 512 + lane * 8];
      s0 = __builtin_amdgcn_mfma_f32_32x32x16_bf16(k0, qf[s + 0], s0, 0, 0, 0);
      s1 = __builtin_amdgcn_mfma_f32_32x32x16_bf16(k1, qf[s + 1], s1, 0, 0, 0);
      s2 = __builtin_amdgcn_mfma_f32_32x32x16_bf16(k2, qf[s + 2], s2, 0, 0, 0);
      s3 = __builtin_amdgcn_mfma_f32_32x32x16_bf16(k3, qf[s + 3], s3, 0, 0, 0);
    }
    __builtin_amdgcn_s_setprio(0);
    // ---- write partial S for partner wave (w^2) into Sx[buf] ----
    f32x4 c[4];
#pragma unroll
    for (int i = 0; i < 4; i++) {
      c[i][0] = (s0[4 * i + 0] + s1[4 * i + 0]) + (s2[4 * i + 0] + s3[4 * i + 0]);
      c[i][1] = (s0[4 * i + 1] + s1[4 * i + 1]) + (s2[4 * i + 1] + s3[4 * i + 1]);
      c[i][2] = (s0[4 * i + 2] + s1[4 * i + 2]) + (s2[4 * i + 2] + s3[4 * i + 2]);
      c[i][3] = (s0[4 * i + 3] + s1[4 * i + 3]) + (s2[4 * i + 3] + s3[4 * i + 3]);
      *(f32x4*)&Sx[buf][w * 1024 + i * 256 + lane * 4] = c[i];
    }
    // ---- THE barrier: Sx visible (lgkm), K staging landed (vmcnt<=8 = V only) ----
    asm volatile("s_waitcnt lgkmcnt(0) vmcnt(8)" ::: "memory");
    __builtin_amdgcn_s_barrier();
    asm volatile("" ::: "memory");
    // lane holds: query ql, keys crow(r,hi) = (r&3) + 8*(r>>2) + 4*hi
    float pl[16];
#pragma unroll
    for (int i = 0; i < 4; i++) {
      f32x4 d = *(const f32x4*)&Sx[buf][(w ^ 2) * 1024 + i * 256 + lane * 4];
      pl[4 * i + 0] = c[i][0] + d[0];
      pl[4 * i + 1] = c[i][1] + d[1];
      pl[4 * i + 2] = c[i][2] + d[2];
      pl[4 * i + 3] = c[i][3] + d[3];
    }
    // ---- softmax: tree max, defer-max, exp2, tree sum ----
    float tm[8];
#pragma unroll
    for (int r = 0; r < 8; r++) tm[r] = fmaxf(pl[r], pl[r + 8]);
    float mx = fmaxf(fmaxf(fmaxf(tm[0], tm[1]), fmaxf(tm[2], tm[3])),
                     fmaxf(fmaxf(tm[4], tm[5]), fmaxf(tm[6], tm[7])));
    mx = fmaxf(mx, __shfl_xor(mx, 32, 64));
    if (__any(mx > mrun + 8.0f)) {            // defer-max (THR=8, validated)
      float mn = fmaxf(mrun, mx);
      float alpha = exp2f(mrun - mn);
      mrun = mn;
      lrun *= alpha;
      float al[16];
#pragma unroll
      for (int r = 0; r < 16; r++)
        al[r] = __shfl(alpha, (r & 3) + 8 * (r >> 2) + 4 * hi, 64);
#pragma unroll
      for (int cb = 0; cb < 4; cb++)
#pragma unroll
        for (int r = 0; r < 16; r++) oacc[cb][r] *= al[r];
    }
    float p[16];
#pragma unroll
    for (int r = 0; r < 16; r++) p[r] = exp2f(pl[r] - mrun);
    float ts[8];
#pragma unroll
    for (int r = 0; r < 8; r++) ts[r] = p[r] + p[r + 8];
    float sum = ((ts[0] + ts[1]) + (ts[2] + ts[3])) + ((ts[4] + ts[5]) + (ts[6] + ts[7]));
    sum += __shfl_xor(sum, 32, 64);
    lrun += sum;
    // ---- P -> A-frags: cvt_pk + halved shuffle (validated mapping) ----
    bf16x8 af0, af1;
#pragma unroll
    for (int ks = 0; ks < 2; ks++) {
      uint32_t Aw, Bw, Cw, Dw;
      asm("v_cvt_pk_bf16_f32 %0, %1, %2" : "=v"(Aw) : "v"(p[8 * ks + 0]), "v"(p[8 * ks + 1]));
      asm("v_cvt_pk_bf16_f32 %0, %1, %2" : "=v"(Bw) : "v"(p[8 * ks + 2]), "v"(p[8 * ks + 3]));
      asm("v_cvt_pk_bf16_f32 %0, %1, %2" : "=v"(Cw) : "v"(p[8 * ks + 4]), "v"(p[8 * ks + 5]));
      asm("v_cvt_pk_bf16_f32 %0, %1, %2" : "=v"(Dw) : "v"(p[8 * ks + 6]), "v"(p[8 * ks + 7]));
      uint32_t Zac = hi ? Aw : Cw;            // one swap serves both output words
      uint32_t Zbd = hi ? Bw : Dw;
      uint32_t Sac = (uint32_t)__shfl_xor((int)Zac, 32, 64);
      uint32_t Sbd = (uint32_t)__shfl_xor((int)Zbd, 32, 64);
      u32x4 u;
      u[0] = hi ? Sac : Aw;                   // == hi?Csw:Aw
      u[1] = hi ? Sbd : Bw;                   // == hi?Dsw:Bw
      u[2] = hi ? Cw : Sac;                   // == hi?Cw:Asw
      u[3] = hi ? Dw : Sbd;                   // == hi?Dw:Bsw
      if (ks == 0) af0 = __builtin_bit_cast(bf16x8, u);
      else         af1 = __builtin_bit_cast(bf16x8, u);
    }
    // ---- O += P @ V: A=P (rows=queries), B=V from REGISTERS; 4 chains ----
#pragma unroll
    for (int cb = 0; cb < 4; cb++) {
      oacc[cb] = __builtin_amdgcn_mfma_f32_32x32x16_bf16(af0, vr[cb][0], oacc[cb], 0, 0, 0);
      oacc[cb] = __builtin_amdgcn_mfma_f32_32x32x16_bf16(af1, vr[cb][1], oacc[cb], 0, 0, 0);
    }
  }
  // ---- epilogue: O /= l, store bf16 row-major (rows=queries crow(r,hi)) ----
  float invl = 1.f / lrun;
  float ir[16];
#pragma unroll
  for (int r = 0; r < 16; r++)
    ir[r] = __shfl(invl, (r & 3) + 8 * (r >> 2) + 4 * hi, 64);
#pragma unroll
  for (int cb = 0; cb < 4; cb++) {
    int col = gg * 128 + cb * 32 + ql;
#pragma unroll
    for (int r = 0; r < 16; r++) {
      int row = q0 + qh * 32 + (r & 3) + 8 * (r >> 2) + 4 * hi;
      O[batch_off + (size_t)row * 512 + col] = f2bf(oacc[cb][r] * ir[r]);
    }
  }
}

extern "C" void kernel_launch(void* const* d_in, const int* in_sizes, int n_in,
                              void* d_out, int out_size, void* d_ws, size_t ws_size,
                              hipStream_t stream) {
  const float* x  = (const float*)d_in[0];
  const float* gs = (const float*)d_in[1];
  const float* gb = (const float*)d_in[2];
  const float* wq = (const float*)d_in[3];
  const float* bq = (const float*)d_in[4];
  const float* wk = (const float*)d_in[5];
  const float* bk = (const float*)d_in[6];
  const float* wv = (const float*)d_in[7];
  const float* bv = (const float*)d_in[8];
  const float* wp = (const float*)d_in[9];
  const float* bp = (const float*)d_in[10];
  float* out = (float*)d_out;

  // ---- workspace layout (~35.7 MB; Q/K live in d_out until final GEMM) ----
  char* ws = (char*)d_ws;
  float2* sums = (float2*)ws;                             // 256 float2 (2 KB)
  short* h    = (short*)(ws + 4096);                      // 16384*512 bf16 (16.78 MB)
  short* wt   = (short*)(ws + 4096 + 16777216);           // 4*512*512 bf16 (2 MB)
  short* Vt   = (short*)(ws + 4096 + 16777216 + 2097152); // [b][c][t] bf16 (16.78 MB)
  short* Qb   = (short*)d_out;                            // 16.78 MB in d_out
  short* Kb   = Qb + 8388608;                             // 16.78 MB in d_out
  short* Ob   = h;                                        // alias: h dead after V GEMM

  gn_stats_k<<<256, 256, 0, stream>>>(x, sums);
  gn_apply_k<<<8192, 256, 0, stream>>>(x, sums, gs, gb, h);
  wconv_k<<<4096, 256, 0, stream>>>(wq, wk, wv, wp, wt);
  qkv_gemm_k<<<dim3(128, 12), 256, 0, stream>>>(h, wt, bq, bk, bv, Qb, Kb, Vt);
  flash_k<<<256, 512, 0, stream>>>(Qb, Kb, Vt, Ob);
  // final projection reads Ob (=h space), x, wt_p; writes d_out (overwrites Q/K)
  gemm_k<<<dim3(128, 4), 256, 0, stream>>>(Ob, wt + 786432, bp, x, out);
}